// Round 2
// 972.825 us; speedup vs baseline: 1.0457x; 1.0457x over previous
//
#include <hip/hip_runtime.h>
#include <stdint.h>

#define NROWS 204800
#define NBLK_Y 1600   // NROWS/128
#define GRP 2048
#define NPG 100

typedef __attribute__((ext_vector_type(4))) float f32x4;
typedef __attribute__((ext_vector_type(8))) short bf16x8;
typedef __attribute__((ext_vector_type(4))) short bf16x4;

__device__ __forceinline__ unsigned bcu(float f){ union{float f;unsigned u;}c; c.f=f; return c.u; }
__device__ __forceinline__ float bcf(unsigned u){ union{unsigned u;float f;}c; c.u=u; return c.f; }
__device__ __forceinline__ short f2bf_rne(float f){ unsigned u=bcu(f); unsigned r=(u+0x7fffu+((u>>16)&1u))>>16; return (short)r; }
// pack two floats -> two bf16 (truncation) in one v_perm
__device__ __forceinline__ unsigned pk_trunc(float lo, float hi){
  return __builtin_amdgcn_perm(bcu(hi), bcu(lo), 0x07060302u);
}
__device__ __forceinline__ f32x4 mfma16(bf16x8 a, bf16x8 b, f32x4 c){
  return __builtin_amdgcn_mfma_f32_16x16x32_bf16(a, b, c, 0, 0, 0);
}
#define BFLY16(v) { v += __shfl_xor(v,1); v += __shfl_xor(v,2); v += __shfl_xor(v,4); v += __shfl_xor(v,8); }

// ---------------- cast p0_W / p1_W to bf16 ----------------
__global__ void k_cast_w(const float* __restrict__ w0, const float* __restrict__ w1,
                         short* __restrict__ out){
  int t = blockIdx.x*256 + threadIdx.x;     // 32768 threads
  const float* src = (t < 16384) ? w0 : w1;
  int base = (t & 16383) * 4;
  f32x4 v = *(const f32x4*)(src + base);
  bf16x4 o; o[0]=f2bf_rne(v[0]); o[1]=f2bf_rne(v[1]); o[2]=f2bf_rne(v[2]); o[3]=f2bf_rne(v[3]);
  *(bf16x4*)(out + ((t<16384)?0:65536) + base) = o;
}

// ---------------- y = x @ W^T + b, bf16 store, col stats ----------------
// v2: tile-outer (mt) loop. B-operand (x rows, full K=256) register-resident
// as bf16 frags; A-operand (W) software-pipelined in half-K double buffers.
// Collapses the per-ks serialized W-load latency chain (16 x ~220cy per
// ks-step in v1) to ~1 covered prefetch per tile.
__global__ void __launch_bounds__(256, 3)
k_gemm_y(const float* __restrict__ x0, const float* __restrict__ x1,
         const short* __restrict__ Wb,
         const float* __restrict__ b0p, const float* __restrict__ b1p,
         short* __restrict__ y0, short* __restrict__ y1,
         float* __restrict__ stats){
  __shared__ float st_sh[4][256][2];
  int bid = blockIdx.x;
  int which = (bid >= NBLK_Y) ? 1 : 0;
  const float* __restrict__ X = which ? x1 : x0;
  short* __restrict__ Y = which ? y1 : y0;
  const short* __restrict__ W = Wb + which*65536;
  const float* __restrict__ bias = which ? b1p : b0p;
  int n0 = (which ? bid - NBLK_Y : bid) * 128;
  int t = threadIdx.x, lane = t & 63, w = t >> 6;
  int l15 = lane & 15, q = lane >> 4;
  int nb = n0 + w*32;

  const short* wrow = W + l15*256;   // A row base for this lane

  // prefetch A frags for mt=0, ks 0..3 (issued before the big x burst)
  bf16x8 wfA[4], wfB[4];
  #pragma unroll
  for (int ks=0; ks<4; ks++)
    wfA[ks] = *(const bf16x8*)(wrow + ks*32 + q*8);

  // x prologue: 32 independent 16B loads per lane, convert fp32->bf16 frags
  bf16x8 xb[2][8];
  #pragma unroll
  for (int g=0; g<2; g++){
    const float* xr = X + (nb + g*16 + l15)*256;
    #pragma unroll
    for (int ks=0; ks<8; ks++){
      int kq = ks*32 + q*8;
      f32x4 a = *(const f32x4*)(xr + kq);
      f32x4 b = *(const f32x4*)(xr + kq + 4);
      int4 p; p.x=(int)pk_trunc(a[0],a[1]); p.y=(int)pk_trunc(a[2],a[3]);
              p.z=(int)pk_trunc(b[0],b[1]); p.w=(int)pk_trunc(b[2],b[3]);
      xb[g][ks] = __builtin_bit_cast(bf16x8, p);
    }
  }

  short* yo0 = Y + (nb + l15)*256 + q*4;
  short* yo1 = Y + (nb + 16 + l15)*256 + q*4;

  #pragma unroll
  for (int mt=0; mt<16; mt++){
    // issue wfB = W[mt], ks 4..7 (consumed after 8 MFMAs)
    #pragma unroll
    for (int ks=0; ks<4; ks++)
      wfB[ks] = *(const bf16x8*)(wrow + mt*4096 + (ks+4)*32 + q*8);
    f32x4 acc0 = f32x4{0,0,0,0}, acc1 = f32x4{0,0,0,0};
    #pragma unroll
    for (int ks=0; ks<4; ks++){
      acc0 = mfma16(wfA[ks], xb[0][ks], acc0);
      acc1 = mfma16(wfA[ks], xb[1][ks], acc1);
    }
    // issue wfA = W[mt+1], ks 0..3 (consumed next tile)
    if (mt < 15){
      #pragma unroll
      for (int ks=0; ks<4; ks++)
        wfA[ks] = *(const bf16x8*)(wrow + (mt+1)*4096 + ks*32 + q*8);
    }
    #pragma unroll
    for (int ks=0; ks<4; ks++){
      acc0 = mfma16(wfB[ks], xb[0][ks+4], acc0);
      acc1 = mfma16(wfB[ks], xb[1][ks+4], acc1);
    }
    // epilogue for tile mt: bias, bf16 store, per-column stats
    f32x4 bb = *(const f32x4*)(bias + mt*16 + q*4);
    f32x4 v0 = acc0 + bb;
    f32x4 v1 = acc1 + bb;
    int2 s0v; s0v.x=(int)pk_trunc(v0[0],v0[1]); s0v.y=(int)pk_trunc(v0[2],v0[3]);
    *(int2*)(yo0 + mt*16) = s0v;
    int2 s1v; s1v.x=(int)pk_trunc(v1[0],v1[1]); s1v.y=(int)pk_trunc(v1[2],v1[3]);
    *(int2*)(yo1 + mt*16) = s1v;
    float sa0=v0[0]+v1[0], sa1=v0[1]+v1[1], sa2=v0[2]+v1[2], sa3=v0[3]+v1[3];
    float qa0=v0[0]*v0[0]+v1[0]*v1[0], qa1=v0[1]*v0[1]+v1[1]*v1[1];
    float qa2=v0[2]*v0[2]+v1[2]*v1[2], qa3=v0[3]*v0[3]+v1[3]*v1[3];
    BFLY16(sa0); BFLY16(sa1); BFLY16(sa2); BFLY16(sa3);
    BFLY16(qa0); BFLY16(qa1); BFLY16(qa2); BFLY16(qa3);
    if (l15 == 0){
      int c0 = mt*16 + q*4;
      st_sh[w][c0+0][0]=sa0; st_sh[w][c0+0][1]=qa0;
      st_sh[w][c0+1][0]=sa1; st_sh[w][c0+1][1]=qa1;
      st_sh[w][c0+2][0]=sa2; st_sh[w][c0+2][1]=qa2;
      st_sh[w][c0+3][0]=sa3; st_sh[w][c0+3][1]=qa3;
    }
  }
  __syncthreads();
  {
    float ss = st_sh[0][t][0]+st_sh[1][t][0]+st_sh[2][t][0]+st_sh[3][t][0];
    float qq = st_sh[0][t][1]+st_sh[1][t][1]+st_sh[2][t][1]+st_sh[3][t][1];
    int rep = bid & 7;
    atomicAdd(&stats[rep*1024 + which*512 + t], ss);
    atomicAdd(&stats[rep*1024 + which*512 + 256 + t], qq);
  }
}

// ---------------- small precompute: BN params, q, qk, cv, cs, wfin, cfin ----------------
__global__ void k_small(const float* __restrict__ inW, const float* __restrict__ inB,
                        const float* __restrict__ mergeB,
                        const float* __restrict__ g0, const float* __restrict__ be0,
                        const float* __restrict__ g1, const float* __restrict__ be1,
                        const float* __restrict__ outW, const float* __restrict__ outB,
                        const float* __restrict__ rout, const float* __restrict__ routB,
                        const float* __restrict__ stats,
                        float* __restrict__ prm, float* __restrict__ qk){
  __shared__ float qv_sh[256], ck_sh[256];
  int t = threadIdx.x;
  const float invN = 1.0f/(float)NROWS;
  float s0=0, sq0=0, s1=0, sq1=0;
  for (int r=0;r<8;r++){
    s0  += stats[r*1024 + t];       sq0 += stats[r*1024 + 256 + t];
    s1  += stats[r*1024 + 512 + t]; sq1 += stats[r*1024 + 768 + t];
  }
  {
    float mu = s0*invN, var = sq0*invN - mu*mu;
    float rs = rsqrtf(var + 1e-5f);
    float a = g0[t]*rs;
    prm[t] = a; prm[512+t] = be0[t] - mu*a;
  }
  {
    float mu = s1*invN, var = sq1*invN - mu*mu;
    float rs = rsqrtf(var + 1e-5f);
    float a = g1[t]*rs;
    prm[256+t] = a; prm[768+t] = be1[t] - mu*a;
  }
  // qvec
  float qs = inB[t];
  for (int k=0;k<256;k++) qs += inW[t*256 + k];
  qv_sh[t] = qs * 0.17677669529663689f;  // 1/sqrt(32)
  // ck
  float cks = inB[256+t];
  for (int m=0;m<256;m++) cks += mergeB[m] * inW[(256+t)*256 + m];
  ck_sh[t] = cks;
  // cv
  float cvs = inB[512+t];
  for (int m=0;m<256;m++) cvs += mergeB[m] * inW[(512+t)*256 + m];
  prm[1024+t] = cvs;
  // wfin
  float wf = 0;
  for (int m=0;m<256;m++) wf += rout[m] * outW[m*256 + t];
  prm[1288+t] = wf;
  __syncthreads();
  // qk[h][m]
  for (int r=0;r<8;r++){
    int idx = r*256 + t; int h = idx>>8, m = idx&255;
    float s = 0;
    for (int d=0;d<32;d++) s += qv_sh[h*32+d] * inW[(256 + h*32 + d)*256 + m];
    qk[h*256+m] = s;
  }
  if (t < 8){
    float cs_ = 0;
    for (int d=0;d<32;d++) cs_ += qv_sh[t*32+d]*ck_sh[t*32+d];
    prm[1280+t] = cs_;
  }
  if (t == 0){
    float cf = routB[0];
    for (int m=0;m<256;m++) cf += rout[m]*outB[m];
    prm[1544] = cf;
  }
}

// ---------------- Wall[c][j]: c<256 -> merge^T Wv^T ; c in 256..263 -> score cols ----------------
__global__ void k_wall(const float* __restrict__ inW, const float* __restrict__ mergeW,
                       const float* __restrict__ qk, short* __restrict__ Wall){
  int c = blockIdx.x; int t = threadIdx.x;  // 272 blocks x 256 threads
  if (c >= 264){
    Wall[c*512 + t] = 0; Wall[c*512 + 256 + t] = 0; return;
  }
  const float* src = (c < 256) ? (inW + (512+c)*256) : (qk + (c-256)*256);
  float a0=0, a1=0;
  for (int m=0;m<256;m++){
    float wm = src[m];
    a0 += wm * mergeW[m*512 + t];
    a1 += wm * mergeW[m*512 + 256 + t];
  }
  Wall[c*512 + t]       = f2bf_rne(a0);
  Wall[c*512 + 256 + t] = f2bf_rne(a1);
}

// ---------------- fused BN+relu -> (v|scores) GEMM -> segment softmax-pool ----------------
// v2: tile-outer loop with register-resident h frags (full K=512) and
// half-K double-buffered Wall frags. Score tile processed first so e0/e1
// exist before the v-tiles' pooling epilogues.
__global__ void __launch_bounds__(256, 2)
k_fused(const short* __restrict__ y0, const short* __restrict__ y1,
        const short* __restrict__ Wall, const float* __restrict__ prm,
        float* __restrict__ num, float* __restrict__ den){
  __shared__ float a_sh[512], b_sh[512], cv_sh[256], cs_sh[8];
  int t = threadIdx.x, lane = t & 63, w = t >> 6;
  int l15 = lane & 15, q = lane >> 4;
  for (int i=t; i<512; i+=256){ a_sh[i] = prm[i]; b_sh[i] = prm[512+i]; }
  cv_sh[t] = prm[1024+t];
  if (t < 8) cs_sh[t] = prm[1280+t];
  __syncthreads();

  int n0 = blockIdx.x*128, nb = n0 + w*32;
  const short* wbase = Wall + l15*512;

  // prefetch wfA for first tile (T=16, the score tile): ks 0..7
  bf16x8 wfA[8], wfB[8];
  #pragma unroll
  for (int ks=0; ks<8; ks++)
    wfA[ks] = *(const bf16x8*)(wbase + 16*8192 + ks*32 + q*8);

  // build h frags (BN + relu + bf16 pack), register-resident for all K=512
  bf16x8 xb[2][16];
  #pragma unroll
  for (int ks=0; ks<16; ks++){
    int jq = ks*32 + q*8;
    const short* ybase = (ks < 8) ? y0 : y1;
    int jj = jq & 255;
    f32x4 paL = *(const f32x4*)&a_sh[jq];  f32x4 paH = *(const f32x4*)&a_sh[jq+4];
    f32x4 pbL = *(const f32x4*)&b_sh[jq];  f32x4 pbH = *(const f32x4*)&b_sh[jq+4];
    #pragma unroll
    for (int g=0; g<2; g++){
      int4 raw = *(const int4*)(ybase + (nb + g*16 + l15)*256 + jj);
      unsigned r0=(unsigned)raw.x, r1=(unsigned)raw.y, r2=(unsigned)raw.z, r3=(unsigned)raw.w;
      float h0 = fmaxf(fmaf(bcf(r0<<16),         paL[0], pbL[0]), 0.f);
      float h1 = fmaxf(fmaf(bcf(r0&0xffff0000u), paL[1], pbL[1]), 0.f);
      float h2 = fmaxf(fmaf(bcf(r1<<16),         paL[2], pbL[2]), 0.f);
      float h3 = fmaxf(fmaf(bcf(r1&0xffff0000u), paL[3], pbL[3]), 0.f);
      float h4 = fmaxf(fmaf(bcf(r2<<16),         paH[0], pbH[0]), 0.f);
      float h5 = fmaxf(fmaf(bcf(r2&0xffff0000u), paH[1], pbH[1]), 0.f);
      float h6 = fmaxf(fmaf(bcf(r3<<16),         paH[2], pbH[2]), 0.f);
      float h7 = fmaxf(fmaf(bcf(r3&0xffff0000u), paH[3], pbH[3]), 0.f);
      int4 pk; pk.x=(int)pk_trunc(h0,h1); pk.y=(int)pk_trunc(h2,h3);
               pk.z=(int)pk_trunc(h4,h5); pk.w=(int)pk_trunc(h6,h7);
      xb[g][ks] = __builtin_bit_cast(bf16x8, pk);
    }
  }

  float e0[4], e1[4];

  // tile order: 16 (scores), then 0..15 (v tiles)
  #pragma unroll
  for (int idx=0; idx<17; idx++){
    const int T = (idx==0) ? 16 : (idx-1);
    // issue wfB = Wall[T], ks 8..15 (consumed after 16 MFMAs)
    #pragma unroll
    for (int ks=0; ks<8; ks++)
      wfB[ks] = *(const bf16x8*)(wbase + T*8192 + (ks+8)*32 + q*8);
    f32x4 acc0 = f32x4{0,0,0,0}, acc1 = f32x4{0,0,0,0};
    #pragma unroll
    for (int ks=0; ks<8; ks++){
      acc0 = mfma16(wfA[ks], xb[0][ks], acc0);
      acc1 = mfma16(wfA[ks], xb[1][ks], acc1);
    }
    // issue wfA for next tile (seq[idx+1] == idx), ks 0..7
    if (idx < 16){
      #pragma unroll
      for (int ks=0; ks<8; ks++)
        wfA[ks] = *(const bf16x8*)(wbase + idx*8192 + ks*32 + q*8);
    }
    #pragma unroll
    for (int ks=0; ks<8; ks++){
      acc0 = mfma16(wfB[ks], xb[0][ks+8], acc0);
      acc1 = mfma16(wfB[ks], xb[1][ks+8], acc1);
    }

    if (T == 16){
      // ---- scores epilogue: e, den ----
      #pragma unroll
      for (int i=0;i<4;i++){
        float cadd = (q<2) ? cs_sh[q*4+i] : 0.f;
        e0[i] = (q<2) ? __expf(acc0[i] + cadd) : 0.f;
        e1[i] = (q<2) ? __expf(acc1[i] + cadd) : 0.f;
      }
      #pragma unroll
      for (int nt=0; nt<2; nt++){
        int tb = nb + nt*16;
        int sg = tb/100; int brow = (sg+1)*100 - tb; bool split = brow < 16;
        float d0[4], d1[4];
        #pragma unroll
        for (int i=0;i<4;i++){
          float ev = nt ? e1[i] : e0[i];
          d0[i] = (l15 < brow) ? ev : 0.f; d1[i] = ev - d0[i];
        }
        BFLY16(d0[0]); BFLY16(d0[1]); BFLY16(d0[2]); BFLY16(d0[3]);
        if (split){ BFLY16(d1[0]); BFLY16(d1[1]); BFLY16(d1[2]); BFLY16(d1[3]); }
        if (l15==0 && q<2){
          #pragma unroll
          for (int i=0;i<4;i++) atomicAdd(&den[sg*8 + q*4 + i], d0[i]);
          if (split){
            #pragma unroll
            for (int i=0;i<4;i++) atomicAdd(&den[(sg+1)*8 + q*4 + i], d1[i]);
          }
        }
      }
    } else {
      // ---- v-tile epilogue: weighted pooling into num ----
      const int h = T>>1, hq = h>>2, hi = h&3;
      f32x4 cvv = *(const f32x4*)&cv_sh[T*16 + q*4];
      #pragma unroll
      for (int nt=0; nt<2; nt++){
        float esrc = nt ? e1[hi] : e0[hi];
        float eb = __shfl(esrc, hq*16 + l15, 64);
        int tb = nb + nt*16;
        int sg = tb/100; int brow = (sg+1)*100 - tb; bool split = brow < 16;
        f32x4 accg = nt ? acc1 : acc0;
        float p0[4], p1[4];
        #pragma unroll
        for (int i=0;i<4;i++){
          float wv = (accg[i] + cvv[i]) * eb;
          p0[i] = (l15 < brow) ? wv : 0.f; p1[i] = wv - p0[i];
        }
        BFLY16(p0[0]); BFLY16(p0[1]); BFLY16(p0[2]); BFLY16(p0[3]);
        if (split){ BFLY16(p1[0]); BFLY16(p1[1]); BFLY16(p1[2]); BFLY16(p1[3]); }
        if (l15==0){
          int c0 = T*16 + q*4;
          #pragma unroll
          for (int i=0;i<4;i++) atomicAdd(&num[sg*256 + c0 + i], p0[i]);
          if (split){
            #pragma unroll
            for (int i=0;i<4;i++) atomicAdd(&num[(sg+1)*256 + c0 + i], p1[i]);
          }
        }
      }
    }
  }
}

// ---------------- final: out[g] = tanh(sum_c num/den * wfin + cfin) ----------------
__global__ void k_out(const float* __restrict__ num, const float* __restrict__ den,
                      const float* __restrict__ prm, float* __restrict__ out){
  int g = blockIdx.x; int lane = threadIdx.x; // 64
  f32x4 nm = *(const f32x4*)(num + g*256 + lane*4);
  f32x4 wf = *(const f32x4*)(prm + 1288 + lane*4);
  float dh = den[g*8 + (lane>>3)];
  float v = (nm[0]*wf[0] + nm[1]*wf[1] + nm[2]*wf[2] + nm[3]*wf[3]) / dh;
  v += __shfl_xor(v,1); v += __shfl_xor(v,2); v += __shfl_xor(v,4);
  v += __shfl_xor(v,8); v += __shfl_xor(v,16); v += __shfl_xor(v,32);
  if (lane==0) out[g] = tanhf(v + prm[1544]);
}

extern "C" void kernel_launch(void* const* d_in, const int* in_sizes, int n_in,
                              void* d_out, int out_size, void* d_ws, size_t ws_size,
                              hipStream_t stream){
  const float* x0      = (const float*)d_in[0];
  const float* x1      = (const float*)d_in[1];
  const float* p0_W    = (const float*)d_in[3];
  const float* p0_b    = (const float*)d_in[4];
  const float* p0_g    = (const float*)d_in[5];
  const float* p0_beta = (const float*)d_in[6];
  const float* p1_W    = (const float*)d_in[7];
  const float* p1_b    = (const float*)d_in[8];
  const float* p1_g    = (const float*)d_in[9];
  const float* p1_beta = (const float*)d_in[10];
  const float* merge_W = (const float*)d_in[11];
  const float* merge_b = (const float*)d_in[12];
  const float* inp_W   = (const float*)d_in[13];
  const float* inp_b   = (const float*)d_in[14];
  const float* out_W   = (const float*)d_in[15];
  const float* out_b   = (const float*)d_in[16];
  const float* ro_W    = (const float*)d_in[17];
  const float* ro_b    = (const float*)d_in[18];
  float* outp = (float*)d_out;

  char* ws = (char*)d_ws;
  short* y0w   = (short*)(ws);
  short* y1w   = (short*)(ws + 104857600);
  short* Wb    = (short*)(ws + 209715200);
  short* Wall  = (short*)(ws + 209977344);
  float* stats = (float*)(ws + 210255872);
  float* num   = (float*)(ws + 210288640);
  float* den   = (float*)(ws + 212385792);
  float* prm   = (float*)(ws + 212451328);
  float* qk    = (float*)(ws + 212459520);

  hipMemsetAsync(ws + 210255872, 0, 2195456, stream);   // stats + num + den

  k_cast_w<<<dim3(128), dim3(256), 0, stream>>>(p0_W, p1_W, Wb);
  k_gemm_y<<<dim3(2*NBLK_Y), dim3(256), 0, stream>>>(x0, x1, Wb, p0_b, p1_b, y0w, y1w, stats);
  k_small<<<dim3(1), dim3(256), 0, stream>>>(inp_W, inp_b, merge_b, p0_g, p0_beta, p1_g, p1_beta,
                                             out_W, out_b, ro_W, ro_b, stats, prm, qk);
  k_wall<<<dim3(272), dim3(256), 0, stream>>>(inp_W, merge_W, qk, Wall);
  k_fused<<<dim3(NBLK_Y), dim3(256), 0, stream>>>(y0w, y1w, Wall, prm, num, den);
  k_out<<<dim3(GRP), dim3(64), 0, stream>>>(num, den, prm, outp);
}